// Round 2
// 1993.226 us; speedup vs baseline: 1.0764x; 1.0764x over previous
//
#include <hip/hip_runtime.h>
#include <math.h>

#define B_ 4
#define L_ 4096
#define D_ 1024
#define NL_ 8921
#define NLP_ 8960  // NL padded to multiple of 128

typedef __bf16 bf16;
typedef bf16 bf16x8 __attribute__((ext_vector_type(8)));
typedef bf16 bf16x4 __attribute__((ext_vector_type(4)));
typedef float f32x4 __attribute__((ext_vector_type(4)));

__device__ __forceinline__ void async_ld16(const void* g, void* l) {
  __builtin_amdgcn_global_load_lds(
      (__attribute__((address_space(1))) const unsigned int*)g,
      (__attribute__((address_space(3))) unsigned int*)l, 16, 0, 0);
}

// ---------------- conversion kernels ----------------

// x fp32 [B,L,D] -> xb bf16 [B,L,D] and xbT bf16 [B,D,L]
__global__ __launch_bounds__(256) void convx_kernel(const float* __restrict__ x,
                                                    bf16* __restrict__ xb,
                                                    bf16* __restrict__ xbT) {
  __shared__ bf16 t[64][65];
  int b = blockIdx.z;
  int l0 = blockIdx.y * 64, d0 = blockIdx.x * 64;
  int tx = threadIdx.x & 63, ty = threadIdx.x >> 6;
  const float* xp = x + (size_t)b * L_ * D_;
  bf16* xbp = xb + (size_t)b * L_ * D_;
#pragma unroll
  for (int i = 0; i < 16; ++i) {
    int l = ty + i * 4;
    float v = xp[(size_t)(l0 + l) * D_ + d0 + tx];
    bf16 bv = (bf16)v;
    xbp[(size_t)(l0 + l) * D_ + d0 + tx] = bv;
    t[l][tx] = bv;
  }
  __syncthreads();
  bf16* xtp = xbT + (size_t)b * D_ * L_;
#pragma unroll
  for (int i = 0; i < 16; ++i) {
    int d = ty + i * 4;
    xtp[(size_t)(d0 + d) * L_ + l0 + tx] = t[tx][d];
  }
}

__global__ __launch_bounds__(256) void convw1_kernel(const float* __restrict__ W,
                                                     bf16* __restrict__ Wb) {
  int i = (blockIdx.x * 256 + threadIdx.x) * 4;
  f32x4 v = *(const f32x4*)(W + i);
  bf16x4 o;
  o[0] = (bf16)v[0]; o[1] = (bf16)v[1]; o[2] = (bf16)v[2]; o[3] = (bf16)v[3];
  *(bf16x4*)(Wb + i) = o;
}

// W2 fp32 [NL,D] -> w2b bf16 [NLP,D], zero pad rows NL..NLP-1
__global__ __launch_bounds__(256) void convw2_kernel(const float* __restrict__ W2,
                                                     bf16* __restrict__ w2b) {
  int i = (blockIdx.x * 256 + threadIdx.x) * 4;
  int n = i >> 10;
  bf16x4 o;
  if (n < NL_) {
    f32x4 v = *(const f32x4*)(W2 + (size_t)i);
    o[0] = (bf16)v[0]; o[1] = (bf16)v[1]; o[2] = (bf16)v[2]; o[3] = (bf16)v[3];
  } else {
    o[0] = o[1] = o[2] = o[3] = (bf16)0.0f;
  }
  *(bf16x4*)(w2b + i) = o;
}

// ---------------- GEMM1: l1 = tanh(xb @ W1b^T), bf16 out ----------------
__global__ __launch_bounds__(256) void gemm1_kernel(const bf16* __restrict__ A,
                                                    const bf16* __restrict__ Bm,
                                                    bf16* __restrict__ C) {
  __shared__ bf16 sA[128 * 64];
  __shared__ bf16 sB[128 * 64];
  int tid = threadIdx.x;
  int wave = tid >> 6, lane = tid & 63;
  int wr = wave >> 1, wc = wave & 1;
  int row0 = blockIdx.y * 128, col0 = blockIdx.x * 128;
  int lm = lane & 15, lk = (lane >> 4) * 8, quad = lane >> 4;
  f32x4 acc[4][4];
#pragma unroll
  for (int i = 0; i < 4; ++i)
#pragma unroll
    for (int j = 0; j < 4; ++j)
#pragma unroll
      for (int r = 0; r < 4; ++r) acc[i][j][r] = 0.f;

  for (int k0 = 0; k0 < D_; k0 += 64) {
#pragma unroll
    for (int j = 0; j < 4; ++j) {
      int e = j * 2048 + wave * 512 + lane * 8;
      int r = e >> 6, kk = e & 63;
      async_ld16(A + (size_t)(row0 + r) * D_ + k0 + kk, (char*)sA + j * 4096 + wave * 1024);
      async_ld16(Bm + (size_t)(col0 + r) * D_ + k0 + kk, (char*)sB + j * 4096 + wave * 1024);
    }
    __syncthreads();
#pragma unroll
    for (int kc = 0; kc < 2; ++kc) {
      bf16x8 af[4], bfr[4];
#pragma unroll
      for (int i = 0; i < 4; ++i)
        af[i] = *(const bf16x8*)(sA + (wr * 64 + i * 16 + lm) * 64 + kc * 32 + lk);
#pragma unroll
      for (int j = 0; j < 4; ++j)
        bfr[j] = *(const bf16x8*)(sB + (wc * 64 + j * 16 + lm) * 64 + kc * 32 + lk);
#pragma unroll
      for (int i = 0; i < 4; ++i)
#pragma unroll
        for (int j = 0; j < 4; ++j)
          acc[i][j] = __builtin_amdgcn_mfma_f32_16x16x32_bf16(af[i], bfr[j], acc[i][j], 0, 0, 0);
    }
    __syncthreads();
  }
#pragma unroll
  for (int i = 0; i < 4; ++i)
#pragma unroll
    for (int j = 0; j < 4; ++j)
#pragma unroll
      for (int r = 0; r < 4; ++r) {
        int row = row0 + wr * 64 + i * 16 + quad * 4 + r;
        int col = col0 + wc * 64 + j * 16 + lm;
        C[(size_t)row * D_ + col] = (bf16)tanhf(acc[i][j][r]);
      }
}

// ---------------- GEMM2 (transposed out): attn_logits[b,n,l] ----------------
// A = w2b [NLP][1024] (rows n), Bm = l1b [16384][1024] (rows m=b*4096+l)
// C[n][m] -> attn[(b*NL+n)*L + l], fp32
// XCD-chunked swizzle: grid (128,70) flat -> each XCD gets 1120 consecutive
// work items -> one w2b panel pinned per XCD L2.
__global__ __launch_bounds__(256) void gemm2_kernel(const bf16* __restrict__ A,
                                                    const bf16* __restrict__ Bm,
                                                    float* __restrict__ attn) {
  __shared__ bf16 sA[128 * 64];
  __shared__ bf16 sB[128 * 64];
  int tid = threadIdx.x;
  int wave = tid >> 6, lane = tid & 63;
  int wr = wave >> 1, wc = wave & 1;
  int flat = blockIdx.x + (blockIdx.y << 7);          // 0..8959
  int id = (flat & 7) * 1120 + (flat >> 3);           // bijective (8960%8==0)
  int row0 = (id >> 7) * 128;                          // n-block
  int col0 = (id & 127) * 128;                         // m-block
  int lm = lane & 15, lk = (lane >> 4) * 8, quad = lane >> 4;
  f32x4 acc[4][4];
#pragma unroll
  for (int i = 0; i < 4; ++i)
#pragma unroll
    for (int j = 0; j < 4; ++j)
#pragma unroll
      for (int r = 0; r < 4; ++r) acc[i][j][r] = 0.f;

  for (int k0 = 0; k0 < D_; k0 += 64) {
#pragma unroll
    for (int j = 0; j < 4; ++j) {
      int e = j * 2048 + wave * 512 + lane * 8;
      int r = e >> 6, kk = e & 63;
      async_ld16(A + (size_t)(row0 + r) * D_ + k0 + kk, (char*)sA + j * 4096 + wave * 1024);
      async_ld16(Bm + (size_t)(col0 + r) * D_ + k0 + kk, (char*)sB + j * 4096 + wave * 1024);
    }
    __syncthreads();
#pragma unroll
    for (int kc = 0; kc < 2; ++kc) {
      bf16x8 af[4], bfr[4];
#pragma unroll
      for (int i = 0; i < 4; ++i)
        af[i] = *(const bf16x8*)(sA + (wr * 64 + i * 16 + lm) * 64 + kc * 32 + lk);
#pragma unroll
      for (int j = 0; j < 4; ++j)
        bfr[j] = *(const bf16x8*)(sB + (wc * 64 + j * 16 + lm) * 64 + kc * 32 + lk);
#pragma unroll
      for (int i = 0; i < 4; ++i)
#pragma unroll
        for (int j = 0; j < 4; ++j)
          acc[i][j] = __builtin_amdgcn_mfma_f32_16x16x32_bf16(af[i], bfr[j], acc[i][j], 0, 0, 0);
    }
    __syncthreads();
  }
#pragma unroll
  for (int i = 0; i < 4; ++i)
#pragma unroll
    for (int j = 0; j < 4; ++j)
#pragma unroll
      for (int r = 0; r < 4; ++r) {
        int n = row0 + wr * 64 + i * 16 + quad * 4 + r;
        int col = col0 + wc * 64 + j * 16 + lm;
        if (n < NL_) {
          int b = col >> 12, l = col & 4095;
          attn[((size_t)b * NL_ + n) * L_ + l] = acc[i][j][r];
        }
      }
}

// ---------------- softmax over contiguous rows of length L ----------------
// Also emits a bf16 copy of the normalized row (for gemm3's A operand) when
// attnb != nullptr. Same cast gemm3 used to do on the fly -> numerically
// identical.
__global__ __launch_bounds__(256) void softmax_kernel(float* __restrict__ attn,
                                                      bf16* __restrict__ attnb) {
  __shared__ float red[8];
  size_t row = blockIdx.x;
  float* p = attn + row * (size_t)L_;
  int tid = threadIdx.x;
  int lane = tid & 63, wave = tid >> 6;
  f32x4 v[4];
  float mx = -3.4e38f;
#pragma unroll
  for (int i = 0; i < 4; ++i) {
    v[i] = *(const f32x4*)(p + i * 1024 + tid * 4);
#pragma unroll
    for (int j = 0; j < 4; ++j) mx = fmaxf(mx, v[i][j]);
  }
#pragma unroll
  for (int o = 32; o > 0; o >>= 1) mx = fmaxf(mx, __shfl_xor(mx, o));
  if (lane == 0) red[wave] = mx;
  __syncthreads();
  mx = fmaxf(fmaxf(red[0], red[1]), fmaxf(red[2], red[3]));
  float sum = 0.f;
#pragma unroll
  for (int i = 0; i < 4; ++i)
#pragma unroll
    for (int j = 0; j < 4; ++j) {
      float e = __expf(v[i][j] - mx);
      v[i][j] = e;
      sum += e;
    }
#pragma unroll
  for (int o = 32; o > 0; o >>= 1) sum += __shfl_xor(sum, o);
  if (lane == 0) red[4 + wave] = sum;
  __syncthreads();
  sum = red[4] + red[5] + red[6] + red[7];
  float inv = 1.0f / sum;
  bf16* q = attnb ? attnb + row * (size_t)L_ : (bf16*)0;
#pragma unroll
  for (int i = 0; i < 4; ++i) {
    f32x4 o4 = v[i];
    o4[0] *= inv; o4[1] *= inv; o4[2] *= inv; o4[3] *= inv;
    *(f32x4*)(p + i * 1024 + tid * 4) = o4;
    if (q) {
      bf16x4 ob;
      ob[0] = (bf16)o4[0]; ob[1] = (bf16)o4[1];
      ob[2] = (bf16)o4[2]; ob[3] = (bf16)o4[3];
      *(bf16x4*)(q + i * 1024 + tid * 4) = ob;
    }
  }
}

// ---------------- GEMM3: out[b] = attn[b] @ xbT[b]^T ----------------
// ABF16=1: A = attnb bf16 [B][NL][L], full async staging.
// ABF16=0: A = attn fp32 [B][NL][L], reg-staged convert (fallback if ws small).
// Bm = xbT[b] bf16 [D][L] (rows d).  C[n][d] -> out[(b*NL+n)*D + d], fp32.
// XCD-chunked swizzle: all 8 D-blocks of one (n-panel, b) land on one XCD,
// so the A panel is fetched once into that XCD's L2 instead of 8 L2s.
template <int ABF16>
__global__ __launch_bounds__(256) void gemm3_kernel(const void* __restrict__ Ap,
                                                    const bf16* __restrict__ xbT,
                                                    float* __restrict__ out) {
  __shared__ bf16 sA[128 * 64];
  __shared__ bf16 sB[128 * 64];
  int tid = threadIdx.x;
  int wave = tid >> 6, lane = tid & 63;
  int wr = wave >> 1, wc = wave & 1;
  int flat = blockIdx.x + (blockIdx.y << 3) + blockIdx.z * 560;  // 0..2239
  int id = (flat & 7) * 280 + (flat >> 3);  // bijective (2240%8==0)
  int col0 = (id & 7) * 128;                 // d-block
  int yz = id >> 3;                          // 0..279
  int b = yz / 70;
  int row0 = (yz - b * 70) * 128;            // n-block
  const bf16* Bb = xbT + (size_t)b * D_ * L_;
  int lm = lane & 15, lk = (lane >> 4) * 8, quad = lane >> 4;
  f32x4 acc[4][4];
#pragma unroll
  for (int i = 0; i < 4; ++i)
#pragma unroll
    for (int j = 0; j < 4; ++j)
#pragma unroll
      for (int r = 0; r < 4; ++r) acc[i][j][r] = 0.f;

  for (int k0 = 0; k0 < L_; k0 += 64) {
    // B stage: async 16B direct-to-LDS
#pragma unroll
    for (int j = 0; j < 4; ++j) {
      int e = j * 2048 + wave * 512 + lane * 8;
      int r = e >> 6, kk = e & 63;
      async_ld16(Bb + (size_t)(col0 + r) * L_ + k0 + kk, (char*)sB + j * 4096 + wave * 1024);
    }
    if constexpr (ABF16) {
      const bf16* Ab = (const bf16*)Ap + (size_t)b * NL_ * L_;
#pragma unroll
      for (int j = 0; j < 4; ++j) {
        int e = j * 2048 + wave * 512 + lane * 8;
        int r = e >> 6, kk = e & 63;
        int gr = row0 + r;
        gr = gr < NL_ ? gr : (NL_ - 1);
        async_ld16(Ab + (size_t)gr * L_ + k0 + kk, (char*)sA + j * 4096 + wave * 1024);
      }
    } else {
      const float* Ab = (const float*)Ap + (size_t)b * NL_ * L_;
#pragma unroll
      for (int u = 0; u < 8; ++u) {
        int e = u * 1024 + tid * 4;
        int r = e >> 6, kk = e & 63;
        int gr = row0 + r;
        gr = gr < NL_ ? gr : (NL_ - 1);
        f32x4 v = *(const f32x4*)(Ab + (size_t)gr * L_ + k0 + kk);
        bf16x4 o;
        o[0] = (bf16)v[0]; o[1] = (bf16)v[1]; o[2] = (bf16)v[2]; o[3] = (bf16)v[3];
        *(bf16x4*)(sA + e) = o;
      }
    }
    __syncthreads();
#pragma unroll
    for (int kc = 0; kc < 2; ++kc) {
      bf16x8 af[4], bfr[4];
#pragma unroll
      for (int i = 0; i < 4; ++i)
        af[i] = *(const bf16x8*)(sA + (wr * 64 + i * 16 + lm) * 64 + kc * 32 + lk);
#pragma unroll
      for (int j = 0; j < 4; ++j)
        bfr[j] = *(const bf16x8*)(sB + (wc * 64 + j * 16 + lm) * 64 + kc * 32 + lk);
#pragma unroll
      for (int i = 0; i < 4; ++i)
#pragma unroll
        for (int j = 0; j < 4; ++j)
          acc[i][j] = __builtin_amdgcn_mfma_f32_16x16x32_bf16(af[i], bfr[j], acc[i][j], 0, 0, 0);
    }
    __syncthreads();
  }
#pragma unroll
  for (int i = 0; i < 4; ++i)
#pragma unroll
    for (int j = 0; j < 4; ++j)
#pragma unroll
      for (int r = 0; r < 4; ++r) {
        int n = row0 + wr * 64 + i * 16 + quad * 4 + r;
        int d = col0 + wc * 64 + j * 16 + lm;
        if (n < NL_) out[((size_t)b * NL_ + n) * D_ + d] = acc[i][j][r];
      }
}

// ---------------- launch ----------------
extern "C" void kernel_launch(void* const* d_in, const int* in_sizes, int n_in,
                              void* d_out, int out_size, void* d_ws, size_t ws_size,
                              hipStream_t stream) {
  const float* x = (const float*)d_in[0];
  const float* W1 = (const float*)d_in[1];
  const float* W2 = (const float*)d_in[2];
  float* out = (float*)d_out;                        // [B, NL, D]
  float* attn = out + (size_t)B_ * NL_ * D_;         // [B, NL, L]

  char* ws = (char*)d_ws;
  // ws layout (bytes):
  //   xb    [B*L*D]   bf16 : 33,554,432
  //   xbT   [B*D*L]   bf16 : 33,554,432
  //   w1b   [D*D]     bf16 :  2,097,152
  //   w2b   [NLP*D]   bf16 : 18,350,080
  //   l1b   [B*L*D]   bf16 : 33,554,432   (end 121,110,528)
  //   attnb [B*NL*L]  bf16 : 292,552,704  (optional, end ~413.7 MB)
  bf16* xb = (bf16*)(ws);
  bf16* xbT = (bf16*)(ws + 33554432);
  bf16* w1b = (bf16*)(ws + 67108864);
  bf16* w2b = (bf16*)(ws + 69206016);
  bf16* l1b = (bf16*)(ws + 87556096);
  size_t need = 121110528ULL + (size_t)B_ * NL_ * L_ * 2;
  bf16* attnb = (ws_size >= need) ? (bf16*)(ws + 121110528) : (bf16*)0;

  convx_kernel<<<dim3(D_ / 64, L_ / 64, B_), 256, 0, stream>>>(x, xb, xbT);
  convw1_kernel<<<(D_ * D_) / 1024, 256, 0, stream>>>(W1, w1b);
  convw2_kernel<<<(NLP_ * D_) / 1024, 256, 0, stream>>>(W2, w2b);

  gemm1_kernel<<<dim3(D_ / 128, (B_ * L_) / 128), 256, 0, stream>>>(xb, w1b, l1b);
  gemm2_kernel<<<dim3((B_ * L_) / 128, NLP_ / 128), 256, 0, stream>>>(w2b, l1b, attn);
  softmax_kernel<<<B_ * NL_, 256, 0, stream>>>(attn, attnb);
  if (attnb)
    gemm3_kernel<1><<<dim3(D_ / 128, NLP_ / 128, B_), 256, 0, stream>>>(attnb, xbT, out);
  else
    gemm3_kernel<0><<<dim3(D_ / 128, NLP_ / 128, B_), 256, 0, stream>>>(attn, xbT, out);
}